// Round 7
// baseline (371.968 us; speedup 1.0000x reference)
//
#include <hip/hip_runtime.h>
#include <cstdint>

#define ALPHA 0.2f

constexpr int NB = 8;
constexpr int NN = 2048;
constexpr int NF = 256;

typedef __attribute__((ext_vector_type(8))) short bf16x8;
typedef __attribute__((ext_vector_type(4))) float f32x4;

__device__ __forceinline__ float bf2f(unsigned short u) {
    union { unsigned int i; float f; } v;
    v.i = ((unsigned int)u) << 16;
    return v.f;
}
__device__ __forceinline__ unsigned short f2bf(float f) {
    union { float f; unsigned int i; } v;
    v.f = f;
    v.i += 0x7fffu + ((v.i >> 16) & 1);  // round-to-nearest-even
    return (unsigned short)(v.i >> 16);
}

// ---------------------------------------------------------------------------
// Kernel 0: WT[f][k] = bf16(W[k][f]) transpose+cast; also zero s1/s2
// ---------------------------------------------------------------------------
__global__ __launch_bounds__(256) void k_wt(const float* __restrict__ W,
                                            unsigned short* __restrict__ WT,
                                            float* __restrict__ s1,
                                            float* __restrict__ s2) {
    const int t = threadIdx.x;
    const int gid = blockIdx.x * 256 + t;
    s1[gid] = 0.f;
    s2[gid] = 0.f;
    const int k = blockIdx.x * 4 + (t >> 6);
    const int f0 = (t & 63) * 4;
    const float4 w = *(const float4*)&W[k * NF + f0];
    WT[(f0 + 0) * NF + k] = f2bf(w.x);
    WT[(f0 + 1) * NF + k] = f2bf(w.y);
    WT[(f0 + 2) * NF + k] = f2bf(w.z);
    WT[(f0 + 3) * NF + k] = f2bf(w.w);
}

// ---------------------------------------------------------------------------
// Kernel 1: WhT = (h @ W)^T per batch, bf16 MFMA; fused s1/s2 epilogue.
// (unchanged — proven correct, ~6-8 us)
// ---------------------------------------------------------------------------
__global__ __launch_bounds__(256, 4) void k_wh(const float* __restrict__ h,
                                               const unsigned short* __restrict__ WT,
                                               const float* __restrict__ a,
                                               unsigned short* __restrict__ WhT,
                                               float* __restrict__ s1,
                                               float* __restrict__ s2) {
    __shared__ __align__(16) unsigned short As[64][72];  // [row][k] bf16
    __shared__ __align__(16) unsigned short Bs[64][72];  // [f][k]  bf16
    const int tid = threadIdx.x;
    const int lane = tid & 63;
    const int l16 = lane & 15;
    const int quad = lane >> 4;
    const int wave = tid >> 6;

    const int p = blockIdx.x;
    const int xcd = p & 7;
    const int q = p >> 3;                       // 0..127
    const int rowTile = xcd + (q >> 2) * 8;     // 0..255
    const int row0 = rowTile * 64;
    const int col0 = (q & 3) * 64;

    const int bb = row0 >> 11;
    const int n0 = row0 & (NN - 1);
    const int mb = (wave & 1) * 32;
    const int nb = (wave >> 1) * 32;

    f32x4 acc[2][2];
#pragma unroll
    for (int mf = 0; mf < 2; ++mf)
#pragma unroll
        for (int nf = 0; nf < 2; ++nf) acc[mf][nf] = (f32x4){0.f, 0.f, 0.f, 0.f};

    const int r0 = tid >> 4;          // 0..15  (+16 per group)
    const int k4 = (tid & 15) * 4;    // 0..60
    const int f0w = tid >> 3;         // 0..31  (+32 per group)
    const int k8 = (tid & 7) * 8;     // 0..56

    const float* hP = &h[(size_t)(row0 + r0) * NF + k4];
    const unsigned short* wP = &WT[(size_t)(col0 + f0w) * NF + k8];

    float4 h0, h1, h2, h3;
    uint4 wv0, wv1;

#define LOADW(K0)                                                      \
    do {                                                               \
        h0 = *(const float4*)&hP[(size_t)(0 * 16) * NF + (K0)];        \
        h1 = *(const float4*)&hP[(size_t)(1 * 16) * NF + (K0)];        \
        h2 = *(const float4*)&hP[(size_t)(2 * 16) * NF + (K0)];        \
        h3 = *(const float4*)&hP[(size_t)(3 * 16) * NF + (K0)];        \
        wv0 = *(const uint4*)&wP[(K0)];                                \
        wv1 = *(const uint4*)&wP[(size_t)32 * NF + (K0)];              \
    } while (0)

    LOADW(0);

    for (int k0 = 0; k0 < NF; k0 += 64) {
        ushort4 o;
        o.x = f2bf(h0.x); o.y = f2bf(h0.y); o.z = f2bf(h0.z); o.w = f2bf(h0.w);
        *(ushort4*)&As[r0 + 0][k4] = o;
        o.x = f2bf(h1.x); o.y = f2bf(h1.y); o.z = f2bf(h1.z); o.w = f2bf(h1.w);
        *(ushort4*)&As[r0 + 16][k4] = o;
        o.x = f2bf(h2.x); o.y = f2bf(h2.y); o.z = f2bf(h2.z); o.w = f2bf(h2.w);
        *(ushort4*)&As[r0 + 32][k4] = o;
        o.x = f2bf(h3.x); o.y = f2bf(h3.y); o.z = f2bf(h3.z); o.w = f2bf(h3.w);
        *(ushort4*)&As[r0 + 48][k4] = o;
        *(uint4*)&Bs[f0w][k8] = wv0;
        *(uint4*)&Bs[f0w + 32][k8] = wv1;
        __syncthreads();
        if (k0 + 64 < NF) LOADW(k0 + 64);
#pragma unroll
        for (int ks = 0; ks < 64; ks += 32) {
            bf16x8 av[2], bv[2];
#pragma unroll
            for (int mf = 0; mf < 2; ++mf)
                av[mf] = *(const bf16x8*)&As[mb + mf * 16 + l16][ks + quad * 8];
#pragma unroll
            for (int nf = 0; nf < 2; ++nf)
                bv[nf] = *(const bf16x8*)&Bs[nb + nf * 16 + l16][ks + quad * 8];
#pragma unroll
            for (int mf = 0; mf < 2; ++mf)
#pragma unroll
                for (int nf = 0; nf < 2; ++nf)
                    acc[mf][nf] = __builtin_amdgcn_mfma_f32_16x16x32_bf16(
                        av[mf], bv[nf], acc[mf][nf], 0, 0, 0);
        }
        __syncthreads();
    }
#undef LOADW

#pragma unroll
    for (int mf = 0; mf < 2; ++mf) {
#pragma unroll
        for (int nf = 0; nf < 2; ++nf) {
            const size_t f = col0 + nb + nf * 16 + l16;
            const int nr = n0 + mb + mf * 16 + quad * 4;
            ushort4 o;
            o.x = f2bf(acc[mf][nf][0]);
            o.y = f2bf(acc[mf][nf][1]);
            o.z = f2bf(acc[mf][nf][2]);
            o.w = f2bf(acc[mf][nf][3]);
            *(ushort4*)&WhT[((size_t)bb * NF + f) * NN + nr] = o;
        }
    }

    float a1v[2], a2v[2];
#pragma unroll
    for (int nf = 0; nf < 2; ++nf) {
        const int f = col0 + nb + nf * 16 + l16;
        a1v[nf] = a[f];
        a2v[nf] = a[NF + f];
    }
#pragma unroll
    for (int mf = 0; mf < 2; ++mf) {
#pragma unroll
        for (int r = 0; r < 4; ++r) {
            float p1 = acc[mf][0][r] * a1v[0] + acc[mf][1][r] * a1v[1];
            float p2 = acc[mf][0][r] * a2v[0] + acc[mf][1][r] * a2v[1];
            p1 += __shfl_xor(p1, 1); p2 += __shfl_xor(p2, 1);
            p1 += __shfl_xor(p1, 2); p2 += __shfl_xor(p2, 2);
            p1 += __shfl_xor(p1, 4); p2 += __shfl_xor(p2, 4);
            p1 += __shfl_xor(p1, 8); p2 += __shfl_xor(p2, 8);
            if (l16 == 0) {
                const int n = n0 + mb + mf * 16 + quad * 4 + r;
                atomicAdd(&s1[bb * NN + n], p1);
                atomicAdd(&s2[bb * NN + n], p2);
            }
        }
    }
}

// ---------------------------------------------------------------------------
// Kernel 2: fused masked softmax + attn @ Wh — BARRIER-FREE register version.
// Round-6 counters (MfmaUtil 6.7, VALUBusy 26.5, HBM 11%, dur 100us) showed
// pure barrier-drain serialization: __syncthreads' vmcnt(0) killed the adj
// prefetch every iteration. Fix: each wave computes the FULL 32x64 P tile
// in registers, directly in mfma A-fragment layout (lane: rows {l16,l16+16},
// j {quad*8..+7, 32+quad*8..+7}); row-sums are running per-lane registers,
// cross-quad-reduced ONCE after the loop via shfl_xor. Zero LDS, zero
// barriers, no inter-wave communication => adj prefetch truly stays in
// flight, waves free-run. 4x redundant exp (~7us chip-wide) is the price.
// bf16 pack: +0x8000 round-half-up + v_perm (1 op/pair vs 4/val RNE).
// Grid 1024 = 8 b (one per XCD) x 64 q-tiles x 2 f-halves; 256 thr.
// ---------------------------------------------------------------------------
__device__ __forceinline__ unsigned int pk2bf(float lo, float hi) {
    union { float f; unsigned int u; } a, b;
    a.f = lo; b.f = hi;
    // dst = [bf16(hi)]<<16 | [bf16(lo)], round-half-up (p >= 0 always here)
    return __builtin_amdgcn_perm(b.u + 0x8000u, a.u + 0x8000u, 0x07060302u);
}
__device__ __forceinline__ float pval(float s1v, float s2j, int a) {
    float x = s1v + s2j;
    x = fmaxf(x, ALPHA * x);     // leaky_relu: valid since 0 < ALPHA < 1
    float e = __expf(x);
    return a > 0 ? e : 0.f;
}

union U8 { bf16x8 v; unsigned int u[4]; };

__global__ __launch_bounds__(256, 3) void k_attn(const unsigned short* __restrict__ WhT,
                                                 const int* __restrict__ adj,
                                                 const float* __restrict__ s1g,
                                                 const float* __restrict__ s2g,
                                                 float* __restrict__ out) {
    const int tid = threadIdx.x;
    const int lane = tid & 63;
    const int l16 = lane & 15;
    const int quad = lane >> 4;
    const int wave = tid >> 6;                  // 0..3
    const int bb = blockIdx.x & 7;              // one batch per XCD
    const int rest = blockIdx.x >> 3;           // 0..127
    const int i0 = (rest >> 1) * 32;            // q-tile base 0..2016
    const int fbase = (rest & 1) * 128 + wave * 32;  // this wave's 32-f slice

    // rows this lane computes P for (A-fragment layout)
    const int r0 = i0 + l16;
    const int r1 = r0 + 16;
    const float s1v0 = s1g[bb * NN + r0];
    const float s1v1 = s1g[bb * NN + r1];

    const size_t adjBase = (size_t)bb * NN * NN;
    const int* adjR0 = &adj[adjBase + (size_t)r0 * NN + quad * 8];
    const int* adjR1 = &adj[adjBase + (size_t)r1 * NN + quad * 8];
    const float* s2P = &s2g[bb * NN + quad * 8];

    const size_t whtBase = (size_t)bb * NF * NN;
    const unsigned short* whB0 = &WhT[whtBase + (size_t)(fbase + l16) * NN + quad * 8];
    const unsigned short* whB1 = whB0 + (size_t)16 * NN;

    f32x4 acc[2][2];
#pragma unroll
    for (int m = 0; m < 2; ++m)
#pragma unroll
        for (int nf = 0; nf < 2; ++nf) acc[m][nf] = (f32x4){0.f, 0.f, 0.f, 0.f};
    float lsum0 = 0.f, lsum1 = 0.f;

#define LOAD_ADJ(A0, A1, A2, A3, B0, B1, B2, B3, J)                           \
    do {                                                                      \
        A0 = *(const int4*)&adjR0[(J)];                                       \
        A1 = *(const int4*)&adjR0[(J) + 4];                                   \
        A2 = *(const int4*)&adjR0[(J) + 32];                                  \
        A3 = *(const int4*)&adjR0[(J) + 36];                                  \
        B0 = *(const int4*)&adjR1[(J)];                                       \
        B1 = *(const int4*)&adjR1[(J) + 4];                                   \
        B2 = *(const int4*)&adjR1[(J) + 32];                                  \
        B3 = *(const int4*)&adjR1[(J) + 36];                                  \
    } while (0)

    // P for one row: 16 values (8 per k-half) -> 2 A-frags + running sum
#define PROW(S1V, QA0, QA1, QA2, QA3, AV0, AV1, LSUM)                         \
    {                                                                         \
        const float p0 = pval(S1V, s2A.x, QA0.x);                             \
        const float p1 = pval(S1V, s2A.y, QA0.y);                             \
        const float p2 = pval(S1V, s2A.z, QA0.z);                             \
        const float p3 = pval(S1V, s2A.w, QA0.w);                             \
        const float p4 = pval(S1V, s2B.x, QA1.x);                             \
        const float p5 = pval(S1V, s2B.y, QA1.y);                             \
        const float p6 = pval(S1V, s2B.z, QA1.z);                             \
        const float p7 = pval(S1V, s2B.w, QA1.w);                             \
        const float q0 = pval(S1V, s2C.x, QA2.x);                             \
        const float q1 = pval(S1V, s2C.y, QA2.y);                             \
        const float q2 = pval(S1V, s2C.z, QA2.z);                             \
        const float q3 = pval(S1V, s2C.w, QA2.w);                             \
        const float q4 = pval(S1V, s2D.x, QA3.x);                             \
        const float q5 = pval(S1V, s2D.y, QA3.y);                             \
        const float q6 = pval(S1V, s2D.z, QA3.z);                             \
        const float q7 = pval(S1V, s2D.w, QA3.w);                             \
        LSUM += (((p0 + p1) + (p2 + p3)) + ((p4 + p5) + (p6 + p7))) +         \
                (((q0 + q1) + (q2 + q3)) + ((q4 + q5) + (q6 + q7)));          \
        U8 u0_, u1_;                                                          \
        u0_.u[0] = pk2bf(p0, p1); u0_.u[1] = pk2bf(p2, p3);                   \
        u0_.u[2] = pk2bf(p4, p5); u0_.u[3] = pk2bf(p6, p7);                   \
        u1_.u[0] = pk2bf(q0, q1); u1_.u[1] = pk2bf(q2, q3);                   \
        u1_.u[2] = pk2bf(q4, q5); u1_.u[3] = pk2bf(q6, q7);                   \
        AV0 = u0_.v; AV1 = u1_.v;                                             \
    }

    // one j-tile: CUR adj regs consumed, NXT adj regs prefetched
#define ITER(T, CA0, CA1, CA2, CA3, CB0, CB1, CB2, CB3,                       \
             XA0, XA1, XA2, XA3, XB0, XB1, XB2, XB3)                          \
    {                                                                         \
        const int j0 = (T) * 64;                                              \
        const float4 s2A = *(const float4*)&s2P[j0];                          \
        const float4 s2B = *(const float4*)&s2P[j0 + 4];                      \
        const float4 s2C = *(const float4*)&s2P[j0 + 32];                     \
        const float4 s2D = *(const float4*)&s2P[j0 + 36];                     \
        const uint4 b00 = *(const uint4*)&whB0[j0];                           \
        const uint4 b01 = *(const uint4*)&whB0[j0 + 32];                      \
        const uint4 b10 = *(const uint4*)&whB1[j0];                           \
        const uint4 b11 = *(const uint4*)&whB1[j0 + 32];                      \
        if ((T) + 1 < NN / 64)                                                \
            LOAD_ADJ(XA0, XA1, XA2, XA3, XB0, XB1, XB2, XB3, j0 + 64);        \
        bf16x8 av00, av01, av10, av11;                                        \
        PROW(s1v0, CA0, CA1, CA2, CA3, av00, av01, lsum0)                     \
        PROW(s1v1, CB0, CB1, CB2, CB3, av10, av11, lsum1)                     \
        acc[0][0] = __builtin_amdgcn_mfma_f32_16x16x32_bf16(                  \
            av00, *(const bf16x8*)&b00, acc[0][0], 0, 0, 0);                  \
        acc[1][0] = __builtin_amdgcn_mfma_f32_16x16x32_bf16(                  \
            av10, *(const bf16x8*)&b00, acc[1][0], 0, 0, 0);                  \
        acc[0][1] = __builtin_amdgcn_mfma_f32_16x16x32_bf16(                  \
            av00, *(const bf16x8*)&b10, acc[0][1], 0, 0, 0);                  \
        acc[1][1] = __builtin_amdgcn_mfma_f32_16x16x32_bf16(                  \
            av10, *(const bf16x8*)&b10, acc[1][1], 0, 0, 0);                  \
        acc[0][0] = __builtin_amdgcn_mfma_f32_16x16x32_bf16(                  \
            av01, *(const bf16x8*)&b01, acc[0][0], 0, 0, 0);                  \
        acc[1][0] = __builtin_amdgcn_mfma_f32_16x16x32_bf16(                  \
            av11, *(const bf16x8*)&b01, acc[1][0], 0, 0, 0);                  \
        acc[0][1] = __builtin_amdgcn_mfma_f32_16x16x32_bf16(                  \
            av01, *(const bf16x8*)&b11, acc[0][1], 0, 0, 0);                  \
        acc[1][1] = __builtin_amdgcn_mfma_f32_16x16x32_bf16(                  \
            av11, *(const bf16x8*)&b11, acc[1][1], 0, 0, 0);                  \
    }

    int4 cA0, cA1, cA2, cA3, cB0, cB1, cB2, cB3;
    int4 nA0 = {0, 0, 0, 0}, nA1 = {0, 0, 0, 0}, nA2 = {0, 0, 0, 0},
         nA3 = {0, 0, 0, 0}, nB0 = {0, 0, 0, 0}, nB1 = {0, 0, 0, 0},
         nB2 = {0, 0, 0, 0}, nB3 = {0, 0, 0, 0};
    LOAD_ADJ(cA0, cA1, cA2, cA3, cB0, cB1, cB2, cB3, 0);

    for (int tt = 0; tt < NN / 128; ++tt) {
        ITER(2 * tt, cA0, cA1, cA2, cA3, cB0, cB1, cB2, cB3,
             nA0, nA1, nA2, nA3, nB0, nB1, nB2, nB3)
        ITER(2 * tt + 1, nA0, nA1, nA2, nA3, nB0, nB1, nB2, nB3,
             cA0, cA1, cA2, cA3, cB0, cB1, cB2, cB3)
    }
#undef ITER
#undef PROW
#undef LOAD_ADJ

    // ---- epilogue: cross-quad row-sum reduce (each lane -> full row sums) ----
    float sum0 = lsum0;
    sum0 += __shfl_xor(sum0, 16);
    sum0 += __shfl_xor(sum0, 32);
    float sum1 = lsum1;
    sum1 += __shfl_xor(sum1, 16);
    sum1 += __shfl_xor(sum1, 32);

#pragma unroll
    for (int m = 0; m < 2; ++m) {
#pragma unroll
        for (int r = 0; r < 4; ++r) {
            const int row = m * 16 + quad * 4 + r;
            // sum for row (quad*4+r [+16]) lives in lane (quad*4+r) of sum0/sum1
            const float sv = m ? __shfl(sum1, quad * 4 + r) : __shfl(sum0, quad * 4 + r);
            const float inv = 1.f / sv;
#pragma unroll
            for (int nf = 0; nf < 2; ++nf) {
                out[((size_t)bb * NN + i0 + row) * NF + fbase + nf * 16 + l16] =
                    acc[m][nf][r] * inv;
            }
        }
    }
}

// ---------------------------------------------------------------------------
extern "C" void kernel_launch(void* const* d_in, const int* in_sizes, int n_in,
                              void* d_out, int out_size, void* d_ws, size_t ws_size,
                              hipStream_t stream) {
    const float* h = (const float*)d_in[0];
    const int* adj = (const int*)d_in[1];
    const float* W = (const float*)d_in[2];
    const float* a = (const float*)d_in[3];
    float* out = (float*)d_out;

    unsigned short* WhT = (unsigned short*)d_ws;  // 8.4 MB bf16, [b][f][n]
    float* s1 = (float*)((char*)d_ws + (size_t)NB * NN * NF * sizeof(unsigned short));
    float* s2 = s1 + (size_t)NB * NN;
    unsigned short* WT = (unsigned short*)(s2 + (size_t)NB * NN);  // 128 KB

    k_wt<<<dim3(64), dim3(256), 0, stream>>>(W, WT, s1, s2);
    k_wh<<<dim3((NB * NN / 64) * (NF / 64)), dim3(256), 0, stream>>>(h, WT, a, WhT, s1, s2);
    // grid = NB batches x (NN/32) q-tiles x 2 f-halves = 1024 blocks
    k_attn<<<dim3(NB * (NN / 32) * 2), dim3(256), 0, stream>>>(WhT, adj, s1, s2, out);
}

// Round 8
// 286.518 us; speedup vs baseline: 1.2982x; 1.2982x over previous
//
#include <hip/hip_runtime.h>
#include <cstdint>

#define ALPHA 0.2f

constexpr int NB = 8;
constexpr int NN = 2048;
constexpr int NF = 256;

typedef __attribute__((ext_vector_type(8))) short bf16x8;
typedef __attribute__((ext_vector_type(4))) float f32x4;

__device__ __forceinline__ float bf2f(unsigned short u) {
    union { unsigned int i; float f; } v;
    v.i = ((unsigned int)u) << 16;
    return v.f;
}
__device__ __forceinline__ unsigned short f2bf(float f) {
    union { float f; unsigned int i; } v;
    v.f = f;
    v.i += 0x7fffu + ((v.i >> 16) & 1);  // round-to-nearest-even
    return (unsigned short)(v.i >> 16);
}

// ---------------------------------------------------------------------------
// Kernel 0: WT[f][k] = bf16(W[k][f]) transpose+cast; also zero s1/s2
// ---------------------------------------------------------------------------
__global__ __launch_bounds__(256) void k_wt(const float* __restrict__ W,
                                            unsigned short* __restrict__ WT,
                                            float* __restrict__ s1,
                                            float* __restrict__ s2) {
    const int t = threadIdx.x;
    const int gid = blockIdx.x * 256 + t;
    s1[gid] = 0.f;
    s2[gid] = 0.f;
    const int k = blockIdx.x * 4 + (t >> 6);
    const int f0 = (t & 63) * 4;
    const float4 w = *(const float4*)&W[k * NF + f0];
    WT[(f0 + 0) * NF + k] = f2bf(w.x);
    WT[(f0 + 1) * NF + k] = f2bf(w.y);
    WT[(f0 + 2) * NF + k] = f2bf(w.z);
    WT[(f0 + 3) * NF + k] = f2bf(w.w);
}

// ---------------------------------------------------------------------------
// Kernel 1: WhT = (h @ W)^T per batch, bf16 MFMA; fused s1/s2 epilogue.
// (unchanged — proven correct, ~6-8 us)
// ---------------------------------------------------------------------------
__global__ __launch_bounds__(256, 4) void k_wh(const float* __restrict__ h,
                                               const unsigned short* __restrict__ WT,
                                               const float* __restrict__ a,
                                               unsigned short* __restrict__ WhT,
                                               float* __restrict__ s1,
                                               float* __restrict__ s2) {
    __shared__ __align__(16) unsigned short As[64][72];  // [row][k] bf16
    __shared__ __align__(16) unsigned short Bs[64][72];  // [f][k]  bf16
    const int tid = threadIdx.x;
    const int lane = tid & 63;
    const int l16 = lane & 15;
    const int quad = lane >> 4;
    const int wave = tid >> 6;

    const int p = blockIdx.x;
    const int xcd = p & 7;
    const int q = p >> 3;                       // 0..127
    const int rowTile = xcd + (q >> 2) * 8;     // 0..255
    const int row0 = rowTile * 64;
    const int col0 = (q & 3) * 64;

    const int bb = row0 >> 11;
    const int n0 = row0 & (NN - 1);
    const int mb = (wave & 1) * 32;
    const int nb = (wave >> 1) * 32;

    f32x4 acc[2][2];
#pragma unroll
    for (int mf = 0; mf < 2; ++mf)
#pragma unroll
        for (int nf = 0; nf < 2; ++nf) acc[mf][nf] = (f32x4){0.f, 0.f, 0.f, 0.f};

    const int r0 = tid >> 4;          // 0..15  (+16 per group)
    const int k4 = (tid & 15) * 4;    // 0..60
    const int f0w = tid >> 3;         // 0..31  (+32 per group)
    const int k8 = (tid & 7) * 8;     // 0..56

    const float* hP = &h[(size_t)(row0 + r0) * NF + k4];
    const unsigned short* wP = &WT[(size_t)(col0 + f0w) * NF + k8];

    float4 h0, h1, h2, h3;
    uint4 wv0, wv1;

#define LOADW(K0)                                                      \
    do {                                                               \
        h0 = *(const float4*)&hP[(size_t)(0 * 16) * NF + (K0)];        \
        h1 = *(const float4*)&hP[(size_t)(1 * 16) * NF + (K0)];        \
        h2 = *(const float4*)&hP[(size_t)(2 * 16) * NF + (K0)];        \
        h3 = *(const float4*)&hP[(size_t)(3 * 16) * NF + (K0)];        \
        wv0 = *(const uint4*)&wP[(K0)];                                \
        wv1 = *(const uint4*)&wP[(size_t)32 * NF + (K0)];              \
    } while (0)

    LOADW(0);

    for (int k0 = 0; k0 < NF; k0 += 64) {
        ushort4 o;
        o.x = f2bf(h0.x); o.y = f2bf(h0.y); o.z = f2bf(h0.z); o.w = f2bf(h0.w);
        *(ushort4*)&As[r0 + 0][k4] = o;
        o.x = f2bf(h1.x); o.y = f2bf(h1.y); o.z = f2bf(h1.z); o.w = f2bf(h1.w);
        *(ushort4*)&As[r0 + 16][k4] = o;
        o.x = f2bf(h2.x); o.y = f2bf(h2.y); o.z = f2bf(h2.z); o.w = f2bf(h2.w);
        *(ushort4*)&As[r0 + 32][k4] = o;
        o.x = f2bf(h3.x); o.y = f2bf(h3.y); o.z = f2bf(h3.z); o.w = f2bf(h3.w);
        *(ushort4*)&As[r0 + 48][k4] = o;
        *(uint4*)&Bs[f0w][k8] = wv0;
        *(uint4*)&Bs[f0w + 32][k8] = wv1;
        __syncthreads();
        if (k0 + 64 < NF) LOADW(k0 + 64);
#pragma unroll
        for (int ks = 0; ks < 64; ks += 32) {
            bf16x8 av[2], bv[2];
#pragma unroll
            for (int mf = 0; mf < 2; ++mf)
                av[mf] = *(const bf16x8*)&As[mb + mf * 16 + l16][ks + quad * 8];
#pragma unroll
            for (int nf = 0; nf < 2; ++nf)
                bv[nf] = *(const bf16x8*)&Bs[nb + nf * 16 + l16][ks + quad * 8];
#pragma unroll
            for (int mf = 0; mf < 2; ++mf)
#pragma unroll
                for (int nf = 0; nf < 2; ++nf)
                    acc[mf][nf] = __builtin_amdgcn_mfma_f32_16x16x32_bf16(
                        av[mf], bv[nf], acc[mf][nf], 0, 0, 0);
        }
        __syncthreads();
    }
#undef LOADW

#pragma unroll
    for (int mf = 0; mf < 2; ++mf) {
#pragma unroll
        for (int nf = 0; nf < 2; ++nf) {
            const size_t f = col0 + nb + nf * 16 + l16;
            const int nr = n0 + mb + mf * 16 + quad * 4;
            ushort4 o;
            o.x = f2bf(acc[mf][nf][0]);
            o.y = f2bf(acc[mf][nf][1]);
            o.z = f2bf(acc[mf][nf][2]);
            o.w = f2bf(acc[mf][nf][3]);
            *(ushort4*)&WhT[((size_t)bb * NF + f) * NN + nr] = o;
        }
    }

    float a1v[2], a2v[2];
#pragma unroll
    for (int nf = 0; nf < 2; ++nf) {
        const int f = col0 + nb + nf * 16 + l16;
        a1v[nf] = a[f];
        a2v[nf] = a[NF + f];
    }
#pragma unroll
    for (int mf = 0; mf < 2; ++mf) {
#pragma unroll
        for (int r = 0; r < 4; ++r) {
            float p1 = acc[mf][0][r] * a1v[0] + acc[mf][1][r] * a1v[1];
            float p2 = acc[mf][0][r] * a2v[0] + acc[mf][1][r] * a2v[1];
            p1 += __shfl_xor(p1, 1); p2 += __shfl_xor(p2, 1);
            p1 += __shfl_xor(p1, 2); p2 += __shfl_xor(p2, 2);
            p1 += __shfl_xor(p1, 4); p2 += __shfl_xor(p2, 4);
            p1 += __shfl_xor(p1, 8); p2 += __shfl_xor(p2, 8);
            if (l16 == 0) {
                const int n = n0 + mb + mf * 16 + quad * 4 + r;
                atomicAdd(&s1[bb * NN + n], p1);
                atomicAdd(&s2[bb * NN + n], p2);
            }
        }
    }
}

// ---------------------------------------------------------------------------
// Kernel 2: fused masked softmax + attn @ Wh.
// Back to the round-0/1 PROVEN pipeline (best measured ~76us): WhsT fully
// LDS-staged, EVERYTHING register-prefetched one full j-tile ahead (loads
// are ~complete by the barrier that drains them), two __syncthreads/iter.
// Delta vs r0: QBLK=16 -> grid 1024 = 8 b x 128 q-tiles, one batch per XCD,
// 4 blocks/CU co-resident (r0 had only 2) for 2x latency overlap. No
// redundant work anywhere (adj read once, P computed once).
// LDS 39.3 KB; 256 thr; per wave 64f x 16q, 8 MFMA/iter.
// ---------------------------------------------------------------------------
__global__ __launch_bounds__(256, 4) void k_attn(const unsigned short* __restrict__ WhT,
                                                 const int* __restrict__ adj,
                                                 const float* __restrict__ s1g,
                                                 const float* __restrict__ s2g,
                                                 float* __restrict__ out) {
    __shared__ __align__(16) unsigned short WhsT[256][72];  // [f][j] bf16
    __shared__ __align__(16) unsigned short Pb[16][72];     // [i][j] bf16
    __shared__ float s1_s[16];
    __shared__ float l_s[16];

    const int tid = threadIdx.x;
    const int lane = tid & 63;
    const int l16 = lane & 15;
    const int quad = lane >> 4;
    const int wave = tid >> 6;                  // 0..3
    const int bb = blockIdx.x & 7;              // one batch per XCD
    const int i0 = (blockIdx.x >> 3) * 16;      // q-tile base 0..2032

    if (tid < 16) {
        s1_s[tid] = s1g[bb * NN + i0 + tid];
        l_s[tid] = 0.f;
    }
    __syncthreads();

    f32x4 acc[4];
#pragma unroll
    for (int nf = 0; nf < 4; ++nf) acc[nf] = (f32x4){0.f, 0.f, 0.f, 0.f};

    const size_t whtBase = (size_t)bb * NF * NN;
    const size_t adjBase = (size_t)bb * NN * NN;
    const float* s2b = s2g + bb * NN;

    // staging geometry: 8 uint4/thread cover WhsT[256][64]
    const int whF = tid >> 3;            // 0..31 (+32 per group, 8 groups)
    const int whK = (tid & 7) * 8;       // 0..56
    const int pIr = tid >> 4;            // 0..15 (one row per 16-thread group)
    const int pKq = (tid & 15) * 4;      // 0..60

    const unsigned short* whP = &WhT[whtBase + (size_t)whF * NN + whK];
    const int* adjP0 = &adj[adjBase + (size_t)(i0 + pIr) * NN + pKq];
    const float* s2P = &s2b[pKq];

    // named prefetch registers (one full j-tile ahead)
    uint4 w0, w1, w2, w3, w4, w5, w6, w7;
    int4 am0;
    float4 sv0;

#define LOAD_TILE(J0)                                                         \
    do {                                                                      \
        const int j0_ = (J0);                                                 \
        w0 = *(const uint4*)&whP[(size_t)(0 * 32) * NN + j0_];                \
        w1 = *(const uint4*)&whP[(size_t)(1 * 32) * NN + j0_];                \
        w2 = *(const uint4*)&whP[(size_t)(2 * 32) * NN + j0_];                \
        w3 = *(const uint4*)&whP[(size_t)(3 * 32) * NN + j0_];                \
        w4 = *(const uint4*)&whP[(size_t)(4 * 32) * NN + j0_];                \
        w5 = *(const uint4*)&whP[(size_t)(5 * 32) * NN + j0_];                \
        w6 = *(const uint4*)&whP[(size_t)(6 * 32) * NN + j0_];                \
        w7 = *(const uint4*)&whP[(size_t)(7 * 32) * NN + j0_];                \
        am0 = *(const int4*)&adjP0[j0_];                                      \
        sv0 = *(const float4*)&s2P[j0_];                                      \
    } while (0)

    LOAD_TILE(0);

    for (int t = 0; t < NN / 64; ++t) {
        // ---- prefetched WhT -> LDS ----
        *(uint4*)&WhsT[whF + 0 * 32][whK] = w0;
        *(uint4*)&WhsT[whF + 1 * 32][whK] = w1;
        *(uint4*)&WhsT[whF + 2 * 32][whK] = w2;
        *(uint4*)&WhsT[whF + 3 * 32][whK] = w3;
        *(uint4*)&WhsT[whF + 4 * 32][whK] = w4;
        *(uint4*)&WhsT[whF + 5 * 32][whK] = w5;
        *(uint4*)&WhsT[whF + 6 * 32][whK] = w6;
        *(uint4*)&WhsT[whF + 7 * 32][whK] = w7;
        // ---- P from prefetched regs: 4 j's for row pIr ----
        {
            const float s1v = s1_s[pIr];
            float x0 = s1v + sv0.x, x1 = s1v + sv0.y;
            float x2 = s1v + sv0.z, x3 = s1v + sv0.w;
            x0 = x0 > 0.f ? x0 : ALPHA * x0;
            x1 = x1 > 0.f ? x1 : ALPHA * x1;
            x2 = x2 > 0.f ? x2 : ALPHA * x2;
            x3 = x3 > 0.f ? x3 : ALPHA * x3;
            const float p0 = am0.x > 0 ? __expf(x0) : 0.f;
            const float p1 = am0.y > 0 ? __expf(x1) : 0.f;
            const float p2 = am0.z > 0 ? __expf(x2) : 0.f;
            const float p3 = am0.w > 0 ? __expf(x3) : 0.f;
            uint2 pk;
            pk.x = (unsigned int)f2bf(p0) | ((unsigned int)f2bf(p1) << 16);
            pk.y = (unsigned int)f2bf(p2) | ((unsigned int)f2bf(p3) << 16);
            *(uint2*)&Pb[pIr][pKq] = pk;
            float ps = (p0 + p1) + (p2 + p3);
            ps += __shfl_xor(ps, 8);
            ps += __shfl_xor(ps, 4);
            ps += __shfl_xor(ps, 2);
            ps += __shfl_xor(ps, 1);
            if ((tid & 15) == 0) l_s[pIr] += ps;  // unique thread per row
        }
        __syncthreads();
        // ---- issue next tile's loads (fly during MFMA + barrier) ----
        if (t + 1 < NN / 64) LOAD_TILE((t + 1) * 64);
        // ---- MFMA: out[16 x 64f per wave] += P[16 x 64j] * WhsT^T ----
        const int f0 = wave * 64;
#pragma unroll
        for (int k0 = 0; k0 < 64; k0 += 32) {
            const bf16x8 af = *(const bf16x8*)&Pb[l16][k0 + quad * 8];
#pragma unroll
            for (int nf = 0; nf < 4; ++nf) {
                const bf16x8 bfr =
                    *(const bf16x8*)&WhsT[f0 + nf * 16 + l16][k0 + quad * 8];
                acc[nf] = __builtin_amdgcn_mfma_f32_16x16x32_bf16(
                    af, bfr, acc[nf], 0, 0, 0);
            }
        }
        __syncthreads();
    }
#undef LOAD_TILE

    // ---- epilogue ----
    if (tid < 16) l_s[tid] = 1.0f / l_s[tid];
    __syncthreads();

    const int f0 = wave * 64;
#pragma unroll
    for (int r = 0; r < 4; ++r) {
        const int row = quad * 4 + r;
        const float inv = l_s[row];
#pragma unroll
        for (int nf = 0; nf < 4; ++nf) {
            out[((size_t)bb * NN + i0 + row) * NF + f0 + nf * 16 + l16] =
                acc[nf][r] * inv;
        }
    }
}

// ---------------------------------------------------------------------------
extern "C" void kernel_launch(void* const* d_in, const int* in_sizes, int n_in,
                              void* d_out, int out_size, void* d_ws, size_t ws_size,
                              hipStream_t stream) {
    const float* h = (const float*)d_in[0];
    const int* adj = (const int*)d_in[1];
    const float* W = (const float*)d_in[2];
    const float* a = (const float*)d_in[3];
    float* out = (float*)d_out;

    unsigned short* WhT = (unsigned short*)d_ws;  // 8.4 MB bf16, [b][f][n]
    float* s1 = (float*)((char*)d_ws + (size_t)NB * NN * NF * sizeof(unsigned short));
    float* s2 = s1 + (size_t)NB * NN;
    unsigned short* WT = (unsigned short*)(s2 + (size_t)NB * NN);  // 128 KB

    k_wt<<<dim3(64), dim3(256), 0, stream>>>(W, WT, s1, s2);
    k_wh<<<dim3((NB * NN / 64) * (NF / 64)), dim3(256), 0, stream>>>(h, WT, a, WhT, s1, s2);
    // grid = NB batches x (NN/16) q-tiles = 1024 blocks, 4 blocks/CU
    k_attn<<<dim3(NB * (NN / 16)), dim3(256), 0, stream>>>(WhT, adj, s1, s2, out);
}

// Round 9
// 237.216 us; speedup vs baseline: 1.5681x; 1.2078x over previous
//
#include <hip/hip_runtime.h>
#include <cstdint>

#define ALPHA 0.2f

constexpr int NB = 8;
constexpr int NN = 2048;
constexpr int NF = 256;

typedef __attribute__((ext_vector_type(8))) short bf16x8;
typedef __attribute__((ext_vector_type(4))) float f32x4;

__device__ __forceinline__ float bf2f(unsigned short u) {
    union { unsigned int i; float f; } v;
    v.i = ((unsigned int)u) << 16;
    return v.f;
}
__device__ __forceinline__ unsigned short f2bf(float f) {
    union { float f; unsigned int i; } v;
    v.f = f;
    v.i += 0x7fffu + ((v.i >> 16) & 1);  // round-to-nearest-even
    return (unsigned short)(v.i >> 16);
}
// pack two non-negative floats to packed bf16 pair (round-half-up), 3 ops
__device__ __forceinline__ unsigned int pk2bf(float lo, float hi) {
    union { float f; unsigned int u; } a, b;
    a.f = lo; b.f = hi;
    return __builtin_amdgcn_perm(b.u + 0x8000u, a.u + 0x8000u, 0x07060302u);
}

// ---------------------------------------------------------------------------
// Kernel 0: WT[f][k] = bf16(W[k][f]) transpose+cast; also zero s1/s2
// ---------------------------------------------------------------------------
__global__ __launch_bounds__(256) void k_wt(const float* __restrict__ W,
                                            unsigned short* __restrict__ WT,
                                            float* __restrict__ s1,
                                            float* __restrict__ s2) {
    const int t = threadIdx.x;
    const int gid = blockIdx.x * 256 + t;
    s1[gid] = 0.f;
    s2[gid] = 0.f;
    const int k = blockIdx.x * 4 + (t >> 6);
    const int f0 = (t & 63) * 4;
    const float4 w = *(const float4*)&W[k * NF + f0];
    WT[(f0 + 0) * NF + k] = f2bf(w.x);
    WT[(f0 + 1) * NF + k] = f2bf(w.y);
    WT[(f0 + 2) * NF + k] = f2bf(w.z);
    WT[(f0 + 3) * NF + k] = f2bf(w.w);
}

// ---------------------------------------------------------------------------
// Kernel 1: WhT = (h @ W)^T per batch, bf16 MFMA; fused s1/s2 epilogue.
// (unchanged — proven correct, ~6-8 us)
// ---------------------------------------------------------------------------
__global__ __launch_bounds__(256, 4) void k_wh(const float* __restrict__ h,
                                               const unsigned short* __restrict__ WT,
                                               const float* __restrict__ a,
                                               unsigned short* __restrict__ WhT,
                                               float* __restrict__ s1,
                                               float* __restrict__ s2) {
    __shared__ __align__(16) unsigned short As[64][72];  // [row][k] bf16
    __shared__ __align__(16) unsigned short Bs[64][72];  // [f][k]  bf16
    const int tid = threadIdx.x;
    const int lane = tid & 63;
    const int l16 = lane & 15;
    const int quad = lane >> 4;
    const int wave = tid >> 6;

    const int p = blockIdx.x;
    const int xcd = p & 7;
    const int q = p >> 3;                       // 0..127
    const int rowTile = xcd + (q >> 2) * 8;     // 0..255
    const int row0 = rowTile * 64;
    const int col0 = (q & 3) * 64;

    const int bb = row0 >> 11;
    const int n0 = row0 & (NN - 1);
    const int mb = (wave & 1) * 32;
    const int nb = (wave >> 1) * 32;

    f32x4 acc[2][2];
#pragma unroll
    for (int mf = 0; mf < 2; ++mf)
#pragma unroll
        for (int nf = 0; nf < 2; ++nf) acc[mf][nf] = (f32x4){0.f, 0.f, 0.f, 0.f};

    const int r0 = tid >> 4;          // 0..15  (+16 per group)
    const int k4 = (tid & 15) * 4;    // 0..60
    const int f0w = tid >> 3;         // 0..31  (+32 per group)
    const int k8 = (tid & 7) * 8;     // 0..56

    const float* hP = &h[(size_t)(row0 + r0) * NF + k4];
    const unsigned short* wP = &WT[(size_t)(col0 + f0w) * NF + k8];

    float4 h0, h1, h2, h3;
    uint4 wv0, wv1;

#define LOADW(K0)                                                      \
    do {                                                               \
        h0 = *(const float4*)&hP[(size_t)(0 * 16) * NF + (K0)];        \
        h1 = *(const float4*)&hP[(size_t)(1 * 16) * NF + (K0)];        \
        h2 = *(const float4*)&hP[(size_t)(2 * 16) * NF + (K0)];        \
        h3 = *(const float4*)&hP[(size_t)(3 * 16) * NF + (K0)];        \
        wv0 = *(const uint4*)&wP[(K0)];                                \
        wv1 = *(const uint4*)&wP[(size_t)32 * NF + (K0)];              \
    } while (0)

    LOADW(0);

    for (int k0 = 0; k0 < NF; k0 += 64) {
        ushort4 o;
        o.x = f2bf(h0.x); o.y = f2bf(h0.y); o.z = f2bf(h0.z); o.w = f2bf(h0.w);
        *(ushort4*)&As[r0 + 0][k4] = o;
        o.x = f2bf(h1.x); o.y = f2bf(h1.y); o.z = f2bf(h1.z); o.w = f2bf(h1.w);
        *(ushort4*)&As[r0 + 16][k4] = o;
        o.x = f2bf(h2.x); o.y = f2bf(h2.y); o.z = f2bf(h2.z); o.w = f2bf(h2.w);
        *(ushort4*)&As[r0 + 32][k4] = o;
        o.x = f2bf(h3.x); o.y = f2bf(h3.y); o.z = f2bf(h3.z); o.w = f2bf(h3.w);
        *(ushort4*)&As[r0 + 48][k4] = o;
        *(uint4*)&Bs[f0w][k8] = wv0;
        *(uint4*)&Bs[f0w + 32][k8] = wv1;
        __syncthreads();
        if (k0 + 64 < NF) LOADW(k0 + 64);
#pragma unroll
        for (int ks = 0; ks < 64; ks += 32) {
            bf16x8 av[2], bv[2];
#pragma unroll
            for (int mf = 0; mf < 2; ++mf)
                av[mf] = *(const bf16x8*)&As[mb + mf * 16 + l16][ks + quad * 8];
#pragma unroll
            for (int nf = 0; nf < 2; ++nf)
                bv[nf] = *(const bf16x8*)&Bs[nb + nf * 16 + l16][ks + quad * 8];
#pragma unroll
            for (int mf = 0; mf < 2; ++mf)
#pragma unroll
                for (int nf = 0; nf < 2; ++nf)
                    acc[mf][nf] = __builtin_amdgcn_mfma_f32_16x16x32_bf16(
                        av[mf], bv[nf], acc[mf][nf], 0, 0, 0);
        }
        __syncthreads();
    }
#undef LOADW

#pragma unroll
    for (int mf = 0; mf < 2; ++mf) {
#pragma unroll
        for (int nf = 0; nf < 2; ++nf) {
            const size_t f = col0 + nb + nf * 16 + l16;
            const int nr = n0 + mb + mf * 16 + quad * 4;
            ushort4 o;
            o.x = f2bf(acc[mf][nf][0]);
            o.y = f2bf(acc[mf][nf][1]);
            o.z = f2bf(acc[mf][nf][2]);
            o.w = f2bf(acc[mf][nf][3]);
            *(ushort4*)&WhT[((size_t)bb * NF + f) * NN + nr] = o;
        }
    }

    float a1v[2], a2v[2];
#pragma unroll
    for (int nf = 0; nf < 2; ++nf) {
        const int f = col0 + nb + nf * 16 + l16;
        a1v[nf] = a[f];
        a2v[nf] = a[NF + f];
    }
#pragma unroll
    for (int mf = 0; mf < 2; ++mf) {
#pragma unroll
        for (int r = 0; r < 4; ++r) {
            float p1 = acc[mf][0][r] * a1v[0] + acc[mf][1][r] * a1v[1];
            float p2 = acc[mf][0][r] * a2v[0] + acc[mf][1][r] * a2v[1];
            p1 += __shfl_xor(p1, 1); p2 += __shfl_xor(p2, 1);
            p1 += __shfl_xor(p1, 2); p2 += __shfl_xor(p2, 2);
            p1 += __shfl_xor(p1, 4); p2 += __shfl_xor(p2, 4);
            p1 += __shfl_xor(p1, 8); p2 += __shfl_xor(p2, 8);
            if (l16 == 0) {
                const int n = n0 + mb + mf * 16 + quad * 4 + r;
                atomicAdd(&s1[bb * NN + n], p1);
                atomicAdd(&s2[bb * NN + n], p2);
            }
        }
    }
}

// ---------------------------------------------------------------------------
// Kernel 2: fused masked softmax + attn @ Wh.
// Structure = the PROVEN r1 kernel (QBLK=32, full WhsT staging, prefetch-1-
// tile-ahead regs, two __syncthreads/iter, grid 512, one batch per XCD,
// 2 blocks/CU) with the per-iteration critical path shortened:
//  * row-sums accumulated in REGISTERS across all 32 iterations; the 4-deep
//    dependent __shfl_xor chain (~120cy each) + l_s LDS RMW now run ONCE
//    after the loop instead of every iteration (saves ~600-700 cy/iter).
//  * s1 hoisted to registers (loop-invariant per thread); s1_s LDS gone.
//  * bf16 pack via v_perm round-half-up (3 ops/pair; validated r7).
// ---------------------------------------------------------------------------
__global__ __launch_bounds__(256, 3) void k_attn(const unsigned short* __restrict__ WhT,
                                                 const int* __restrict__ adj,
                                                 const float* __restrict__ s1g,
                                                 const float* __restrict__ s2g,
                                                 float* __restrict__ out) {
    __shared__ __align__(16) unsigned short WhsT[256][72];  // [f][j]
    __shared__ __align__(16) unsigned short Pb[32][72];     // [i][j]
    __shared__ float l_s[32];

    const int tid = threadIdx.x;
    const int lane = tid & 63;
    const int l16 = lane & 15;
    const int quad = lane >> 4;
    const int wave = tid >> 6;
    const int bb = blockIdx.x & 7;           // one batch per XCD
    const int i0 = (blockIdx.x >> 3) * 32;   // q-tile base

    f32x4 acc[2][4];
#pragma unroll
    for (int m = 0; m < 2; ++m)
#pragma unroll
        for (int nf = 0; nf < 4; ++nf) acc[m][nf] = (f32x4){0.f, 0.f, 0.f, 0.f};

    const size_t whtBase = (size_t)bb * NF * NN;
    const size_t adjBase = (size_t)bb * NN * NN;
    const float* s2b = s2g + bb * NN;

    // per-thread geometry
    const int whF = tid >> 3;            // 0..255 (it adds 32 per step)
    const int whK = (tid & 7) * 8;       // 0..56
    const int pIr = tid >> 4;            // 0..15 (rows pIr, pIr+16)
    const int pKq = (tid & 15) * 4;      // 0..60

    const unsigned short* whP = &WhT[whtBase + (size_t)whF * NN + whK];
    const int* adjP0 = &adj[adjBase + (size_t)(i0 + pIr) * NN + pKq];
    const int* adjP1 = adjP0 + 16 * NN;
    const float* s2P = &s2b[pKq];

    // loop-invariant s1 in registers (was s1_s LDS reads)
    const float s1v0 = s1g[bb * NN + i0 + pIr];
    const float s1v1 = s1g[bb * NN + i0 + pIr + 16];
    // register row-sum accumulators
    float lsum0 = 0.f, lsum1 = 0.f;

    // named prefetch registers
    uint4 w0, w1, w2, w3, w4, w5, w6, w7;
    int4 am0, am1;
    float4 sv0;

#define LOAD_TILE(J0)                                                         \
    do {                                                                      \
        const int j0_ = (J0);                                                 \
        w0 = *(const uint4*)&whP[(size_t)(0 * 32) * NN + j0_];                \
        w1 = *(const uint4*)&whP[(size_t)(1 * 32) * NN + j0_];                \
        w2 = *(const uint4*)&whP[(size_t)(2 * 32) * NN + j0_];                \
        w3 = *(const uint4*)&whP[(size_t)(3 * 32) * NN + j0_];                \
        w4 = *(const uint4*)&whP[(size_t)(4 * 32) * NN + j0_];                \
        w5 = *(const uint4*)&whP[(size_t)(5 * 32) * NN + j0_];                \
        w6 = *(const uint4*)&whP[(size_t)(6 * 32) * NN + j0_];                \
        w7 = *(const uint4*)&whP[(size_t)(7 * 32) * NN + j0_];                \
        am0 = *(const int4*)&adjP0[j0_];                                      \
        am1 = *(const int4*)&adjP1[j0_];                                      \
        sv0 = *(const float4*)&s2P[j0_];                                      \
    } while (0)

    LOAD_TILE(0);

    for (int t = 0; t < NN / 64; ++t) {
        // ---- prefetched WhT -> LDS ----
        *(uint4*)&WhsT[whF + 0 * 32][whK] = w0;
        *(uint4*)&WhsT[whF + 1 * 32][whK] = w1;
        *(uint4*)&WhsT[whF + 2 * 32][whK] = w2;
        *(uint4*)&WhsT[whF + 3 * 32][whK] = w3;
        *(uint4*)&WhsT[whF + 4 * 32][whK] = w4;
        *(uint4*)&WhsT[whF + 5 * 32][whK] = w5;
        *(uint4*)&WhsT[whF + 6 * 32][whK] = w6;
        *(uint4*)&WhsT[whF + 7 * 32][whK] = w7;
        // ---- P: row pIr (am0) and row pIr+16 (am1), 4 j's each ----
        {
            float x0 = s1v0 + sv0.x, x1 = s1v0 + sv0.y;
            float x2 = s1v0 + sv0.z, x3 = s1v0 + sv0.w;
            x0 = fmaxf(x0, ALPHA * x0);
            x1 = fmaxf(x1, ALPHA * x1);
            x2 = fmaxf(x2, ALPHA * x2);
            x3 = fmaxf(x3, ALPHA * x3);
            const float p0 = am0.x > 0 ? __expf(x0) : 0.f;
            const float p1 = am0.y > 0 ? __expf(x1) : 0.f;
            const float p2 = am0.z > 0 ? __expf(x2) : 0.f;
            const float p3 = am0.w > 0 ? __expf(x3) : 0.f;
            uint2 pk;
            pk.x = pk2bf(p0, p1);
            pk.y = pk2bf(p2, p3);
            *(uint2*)&Pb[pIr][pKq] = pk;
            lsum0 += (p0 + p1) + (p2 + p3);
        }
        {
            float x0 = s1v1 + sv0.x, x1 = s1v1 + sv0.y;
            float x2 = s1v1 + sv0.z, x3 = s1v1 + sv0.w;
            x0 = fmaxf(x0, ALPHA * x0);
            x1 = fmaxf(x1, ALPHA * x1);
            x2 = fmaxf(x2, ALPHA * x2);
            x3 = fmaxf(x3, ALPHA * x3);
            const float p0 = am1.x > 0 ? __expf(x0) : 0.f;
            const float p1 = am1.y > 0 ? __expf(x1) : 0.f;
            const float p2 = am1.z > 0 ? __expf(x2) : 0.f;
            const float p3 = am1.w > 0 ? __expf(x3) : 0.f;
            uint2 pk;
            pk.x = pk2bf(p0, p1);
            pk.y = pk2bf(p2, p3);
            *(uint2*)&Pb[pIr + 16][pKq] = pk;
            lsum1 += (p0 + p1) + (p2 + p3);
        }
        __syncthreads();
        // ---- issue next tile's loads (fly during MFMA + barrier) ----
        if (t + 1 < NN / 64) LOAD_TILE((t + 1) * 64);
        // ---- MFMA: out[32 x 64f per wave] += P[32 x 64j] * WhsT^T ----
        const int f0 = wave * 64;
#pragma unroll
        for (int k0 = 0; k0 < 64; k0 += 32) {
            bf16x8 af[2];
#pragma unroll
            for (int m = 0; m < 2; ++m)
                af[m] = *(const bf16x8*)&Pb[m * 16 + l16][k0 + quad * 8];
#pragma unroll
            for (int nf = 0; nf < 4; ++nf) {
                const bf16x8 bfr =
                    *(const bf16x8*)&WhsT[f0 + nf * 16 + l16][k0 + quad * 8];
#pragma unroll
                for (int m = 0; m < 2; ++m)
                    acc[m][nf] = __builtin_amdgcn_mfma_f32_16x16x32_bf16(
                        af[m], bfr, acc[m][nf], 0, 0, 0);
            }
        }
        __syncthreads();
    }
#undef LOAD_TILE

    // ---- one-time row-sum reduce (16 threads per row, consecutive lanes) ----
    lsum0 += __shfl_xor(lsum0, 1);
    lsum0 += __shfl_xor(lsum0, 2);
    lsum0 += __shfl_xor(lsum0, 4);
    lsum0 += __shfl_xor(lsum0, 8);
    lsum1 += __shfl_xor(lsum1, 1);
    lsum1 += __shfl_xor(lsum1, 2);
    lsum1 += __shfl_xor(lsum1, 4);
    lsum1 += __shfl_xor(lsum1, 8);
    if ((tid & 15) == 0) {
        l_s[pIr] = 1.0f / lsum0;
        l_s[pIr + 16] = 1.0f / lsum1;
    }
    __syncthreads();

    // ---- epilogue ----
    const int f0 = wave * 64;
#pragma unroll
    for (int m = 0; m < 2; ++m) {
#pragma unroll
        for (int r = 0; r < 4; ++r) {
            const int row = m * 16 + quad * 4 + r;
            const float inv = l_s[row];
#pragma unroll
            for (int nf = 0; nf < 4; ++nf) {
                out[((size_t)bb * NN + i0 + row) * NF + f0 + nf * 16 + l16] =
                    acc[m][nf][r] * inv;
            }
        }
    }
}

// ---------------------------------------------------------------------------
extern "C" void kernel_launch(void* const* d_in, const int* in_sizes, int n_in,
                              void* d_out, int out_size, void* d_ws, size_t ws_size,
                              hipStream_t stream) {
    const float* h = (const float*)d_in[0];
    const int* adj = (const int*)d_in[1];
    const float* W = (const float*)d_in[2];
    const float* a = (const float*)d_in[3];
    float* out = (float*)d_out;

    unsigned short* WhT = (unsigned short*)d_ws;  // 8.4 MB bf16, [b][f][n]
    float* s1 = (float*)((char*)d_ws + (size_t)NB * NN * NF * sizeof(unsigned short));
    float* s2 = s1 + (size_t)NB * NN;
    unsigned short* WT = (unsigned short*)(s2 + (size_t)NB * NN);  // 128 KB

    k_wt<<<dim3(64), dim3(256), 0, stream>>>(W, WT, s1, s2);
    k_wh<<<dim3((NB * NN / 64) * (NF / 64)), dim3(256), 0, stream>>>(h, WT, a, WhT, s1, s2);
    // grid = NB batches x (NN/32) q-tiles = 512 blocks (one batch per XCD)
    k_attn<<<dim3(NB * (NN / 32)), dim3(256), 0, stream>>>(WhT, adj, s1, s2, out);
}